// Round 3
// baseline (171.665 us; speedup 1.0000x reference)
//
#include <hip/hip_runtime.h>

#define N_DOWN  50000
#define N_ABOVE 100000
#define DIM     256
#define FAN     5
#define K1      1280      // FAN * DIM
#define MPAD    100096    // 391 * 256
#define NT1     40        // K1 / 32
#define NT2     8         // DIM / 32
#define BUFE    8192      // 128 lines * 64 elems, one ring slot of one operand

typedef __bf16 bf16x8 __attribute__((ext_vector_type(8)));
typedef float  f32x4  __attribute__((ext_vector_type(4)));

__device__ __forceinline__ unsigned short f2bf(float f) {
  unsigned u = __builtin_bit_cast(unsigned, f);
  u += 0x7FFFu + ((u >> 16) & 1u);          // RNE round to bf16
  return (unsigned short)(u >> 16);
}

__device__ __forceinline__ void gload16(const unsigned short* g, unsigned short* l) {
  __builtin_amdgcn_global_load_lds(
      (const __attribute__((address_space(1))) void*)g,
      (__attribute__((address_space(3))) void*)l, 16, 0, 0);
}

#define BAR()   __builtin_amdgcn_s_barrier()
#define LGKM0() do { asm volatile("s_waitcnt lgkmcnt(0)" ::: "memory"); \
                     __builtin_amdgcn_sched_barrier(0); } while (0)
#define VMW4()  do { asm volatile("s_waitcnt vmcnt(4)" ::: "memory"); \
                     __builtin_amdgcn_sched_barrier(0); } while (0)
#define VMW0()  do { asm volatile("s_waitcnt vmcnt(0)" ::: "memory"); \
                     __builtin_amdgcn_sched_barrier(0); } while (0)

// ---- prep ----
__global__ void k_prep_inv(int* __restrict__ inv, unsigned short* __restrict__ hbf) {
  int t = blockIdx.x * 256 + threadIdx.x;
  if (t < N_ABOVE) inv[t] = N_DOWN;                 // sentinel -> zero row
  if (t < DIM)     hbf[(size_t)N_DOWN * DIM + t] = 0;
}

__global__ void k_scatter(const int* __restrict__ idx, int* __restrict__ inv) {
  int t = blockIdx.x * 256 + threadIdx.x;
  if (t < N_DOWN) inv[idx[t]] = t;
}

__global__ void k_h2bf(const float* __restrict__ h, unsigned short* __restrict__ hbf) {
  int t = blockIdx.x * 256 + threadIdx.x;           // grid sized exactly: 12500*256
  float4 v = ((const float4*)h)[t];
  ushort4 o;
  o.x = f2bf(v.x); o.y = f2bf(v.y); o.z = f2bf(v.z); o.w = f2bf(v.w);
  ((ushort4*)hbf)[t] = o;
}

// in: [K][N] f32 row-major -> out: [N][K] bf16 row-major
__global__ void k_transpose_bf(const float* __restrict__ in, unsigned short* __restrict__ out,
                               int K, int N) {
  __shared__ float tile[64][65];
  int k0 = blockIdx.x * 64, n0 = blockIdx.y * 64;
  int c = threadIdx.x & 63, rb = threadIdx.x >> 6;
#pragma unroll
  for (int rr = 0; rr < 16; ++rr) {
    int row = rb + rr * 4;
    tile[row][c] = in[(size_t)(k0 + row) * N + n0 + c];
  }
  __syncthreads();
#pragma unroll
  for (int rr = 0; rr < 16; ++rr) {
    int nr = rb + rr * 4;
    out[(size_t)(n0 + nr) * K + k0 + c] = f2bf(tile[c][nr]);
  }
}

// LDS pair-row layout (per 256x32 tile, per operand):
//   elem (row r, k) lives at line = r>>1, chunk = (((r&1)<<2)|(k>>3)) ^ (line&7), e = k&7
//   addr(elems) = line*64 + chunk*8 + e.  Staging is lane-linear: wave-write of
//   8 lines = 1 KiB; lane l covers (line = base + (l>>3), chunk = l&7) whose
//   inverse-swizzled global source is row = 2*line + (u>>2), kc = (u&3)*8 with
//   u = (l&7) ^ (line&7).

// ---- GEMM1 (256^2, ring-3, counted vmcnt): hid = relu(gather(hbf)@W1 + b1) ----
__global__ __launch_bounds__(512, 2) void k_gemm1(
    const unsigned short* __restrict__ hbf,   // [N_DOWN+1][256] bf16
    const unsigned short* __restrict__ w1t,   // [256][1280]  bf16 (W1^T)
    const float* __restrict__ b1,
    const int* __restrict__ inv,              // [N_ABOVE]
    const int* __restrict__ jarr,             // [N_ABOVE*FAN]
    unsigned short* __restrict__ hid)         // [MPAD][256] bf16
{
  extern __shared__ __align__(16) unsigned short smem[];   // A ring [0,3*BUFE), B ring after
  unsigned short* Aring = smem;
  unsigned short* Bring = smem + 3 * BUFE;

  const int tid = threadIdx.x;
  const int w = tid >> 6, l = tid & 63;
  const int m0 = blockIdx.x * 256;
  const int wm = w & 1, wn = w >> 1;          // 2M x 4N waves; per-wave 128x64

  // ---- staging precompute (2 writes j=0,1 per operand per tile) ----
  const int line0 = w * 16 + (l >> 3);
  const int line1 = line0 + 8;
  const int u0 = (l & 7) ^ (line0 & 7);
  const int u1 = (l & 7) ^ (line1 & 7);
  const int r0 = 2 * line0 + (u0 >> 2), kc0 = (u0 & 3) * 8;
  const int r1 = 2 * line1 + (u1 >> 2), kc1 = (u1 & 3) * 8;
  const int adst0 = w * 1024;                 // (w*16)*64
  const int adst1 = w * 1024 + 512;

  // gather sources for my 2 A-rows, 5 segments each (named regs)
  const int gm0 = min(m0 + r0, N_ABOVE - 1);
  const int gm1 = min(m0 + r1, N_ABOVE - 1);
  const int s00 = inv[jarr[(size_t)gm0 * FAN + 0]], s01 = inv[jarr[(size_t)gm0 * FAN + 1]],
            s02 = inv[jarr[(size_t)gm0 * FAN + 2]], s03 = inv[jarr[(size_t)gm0 * FAN + 3]],
            s04 = inv[jarr[(size_t)gm0 * FAN + 4]];
  const int s10 = inv[jarr[(size_t)gm1 * FAN + 0]], s11 = inv[jarr[(size_t)gm1 * FAN + 1]],
            s12 = inv[jarr[(size_t)gm1 * FAN + 2]], s13 = inv[jarr[(size_t)gm1 * FAN + 3]],
            s14 = inv[jarr[(size_t)gm1 * FAN + 4]];

  // ---- fragment read offsets (t-invariant) ----
  int aoff[8], boff[4];
#pragma unroll
  for (int mf = 0; mf < 8; ++mf) {
    int row = wm * 128 + mf * 16 + (l & 15);
    int line = row >> 1;
    int chk = (((row & 1) << 2) | (l >> 4)) ^ (line & 7);
    aoff[mf] = line * 64 + chk * 8;
  }
#pragma unroll
  for (int nf = 0; nf < 4; ++nf) {
    int row = wn * 64 + nf * 16 + (l & 15);
    int line = row >> 1;
    int chk = (((row & 1) << 2) | (l >> 4)) ^ (line & 7);
    boff[nf] = line * 64 + chk * 8;
  }

  VMW0();   // retire the gather loads: clean VMEM FIFO for counted staging

#define STAGE_A1(tt, Abuf, S0, S1) do {                                          \
    gload16(hbf + ((size_t)(S0) << 8) + (((tt) & 7) << 5) + kc0, (Abuf) + adst0);\
    gload16(hbf + ((size_t)(S1) << 8) + (((tt) & 7) << 5) + kc1, (Abuf) + adst1);\
  } while (0)
#define STAGE_B1(tt, Bbuf) do {                                                  \
    gload16(w1t + (size_t)r0 * K1 + ((tt) << 5) + kc0, (Bbuf) + adst0);          \
    gload16(w1t + (size_t)r1 * K1 + ((tt) << 5) + kc1, (Bbuf) + adst1);          \
  } while (0)

  // prologue: stage tiles 0 and 1 (segment u=0)
  STAGE_A1(0, Aring, s00, s10);
  STAGE_B1(0, Bring);
  STAGE_A1(1, Aring + BUFE, s00, s10);
  STAGE_B1(1, Bring + BUFE);
  VMW4();                                    // tile 0 landed (tile 1 in flight)
  BAR();

  f32x4 acc[8][4] = {};
  int cur = 0, nx2 = 2;

#pragma unroll 1
  for (int t = 0; t < NT1; ++t) {
    unsigned short* Ac = Aring + cur * BUFE;
    unsigned short* Bc = Bring + cur * BUFE;
    unsigned short* An = Aring + nx2 * BUFE;
    unsigned short* Bn = Bring + nx2 * BUFE;
    const int t2 = t + 2;
    const bool do_stage = (t2 < NT1);
    const int u = t2 >> 3;
    const int ss0 = u == 0 ? s00 : u == 1 ? s01 : u == 2 ? s02 : u == 3 ? s03 : s04;
    const int ss1 = u == 0 ? s10 : u == 1 ? s11 : u == 2 ? s12 : u == 3 ? s13 : s14;

    // ---------- phase 0: mf 0-3 ----------
    bf16x8 af[4], bfr[4];
#pragma unroll
    for (int mf = 0; mf < 4; ++mf) af[mf] = *(const bf16x8*)(Ac + aoff[mf]);
#pragma unroll
    for (int nf = 0; nf < 4; ++nf) bfr[nf] = *(const bf16x8*)(Bc + boff[nf]);
    if (do_stage) STAGE_A1(t2, An, ss0, ss1);
    BAR();
    LGKM0();
    __builtin_amdgcn_s_setprio(1);
#pragma unroll
    for (int mf = 0; mf < 4; ++mf)
#pragma unroll
      for (int nf = 0; nf < 4; ++nf)
        acc[mf][nf] = __builtin_amdgcn_mfma_f32_16x16x32_bf16(af[mf], bfr[nf], acc[mf][nf], 0, 0, 0);
    __builtin_amdgcn_s_setprio(0);
    BAR();

    // ---------- phase 1: mf 4-7 (B-frags reused in regs) ----------
#pragma unroll
    for (int mf = 0; mf < 4; ++mf) af[mf] = *(const bf16x8*)(Ac + aoff[4 + mf]);
    if (do_stage) STAGE_B1(t2, Bn);
    BAR();
    LGKM0();
    __builtin_amdgcn_s_setprio(1);
#pragma unroll
    for (int mf = 0; mf < 4; ++mf)
#pragma unroll
      for (int nf = 0; nf < 4; ++nf)
        acc[4 + mf][nf] = __builtin_amdgcn_mfma_f32_16x16x32_bf16(af[mf], bfr[nf], acc[4 + mf][nf], 0, 0, 0);
    __builtin_amdgcn_s_setprio(0);
    if (t < NT1 - 2) { VMW4(); } else if (t == NT1 - 2) { VMW0(); }
    BAR();

    cur = (cur == 2) ? 0 : cur + 1;
    nx2 = (nx2 == 2) ? 0 : nx2 + 1;
  }

  // epilogue: bias + relu -> bf16
#pragma unroll
  for (int nf = 0; nf < 4; ++nf) {
    int gn = wn * 64 + nf * 16 + (l & 15);
    float bias = b1[gn];
#pragma unroll
    for (int mf = 0; mf < 8; ++mf) {
      int gr0 = m0 + wm * 128 + mf * 16 + (l >> 4) * 4;
#pragma unroll
      for (int q = 0; q < 4; ++q) {
        float v = acc[mf][nf][q] + bias;
        v = v > 0.f ? v : 0.f;
        hid[(size_t)(gr0 + q) * DIM + gn] = f2bf(v);
      }
    }
  }
#undef STAGE_A1
#undef STAGE_B1
}

// ---- GEMM2 (same structure, no gather, NT=8): out = hid @ W2 + b2 (f32) ----
__global__ __launch_bounds__(512, 2) void k_gemm2(
    const unsigned short* __restrict__ hid,   // [MPAD][256] bf16
    const unsigned short* __restrict__ w2t,   // [256][256] bf16 (W2^T)
    const float* __restrict__ b2,
    float* __restrict__ out)
{
  extern __shared__ __align__(16) unsigned short smem[];
  unsigned short* Aring = smem;
  unsigned short* Bring = smem + 3 * BUFE;

  const int tid = threadIdx.x;
  const int w = tid >> 6, l = tid & 63;
  const int m0 = blockIdx.x * 256;
  const int wm = w & 1, wn = w >> 1;

  const int line0 = w * 16 + (l >> 3);
  const int line1 = line0 + 8;
  const int u0 = (l & 7) ^ (line0 & 7);
  const int u1 = (l & 7) ^ (line1 & 7);
  const int r0 = 2 * line0 + (u0 >> 2), kc0 = (u0 & 3) * 8;
  const int r1 = 2 * line1 + (u1 >> 2), kc1 = (u1 & 3) * 8;
  const int adst0 = w * 1024;
  const int adst1 = w * 1024 + 512;

  int aoff[8], boff[4];
#pragma unroll
  for (int mf = 0; mf < 8; ++mf) {
    int row = wm * 128 + mf * 16 + (l & 15);
    int line = row >> 1;
    int chk = (((row & 1) << 2) | (l >> 4)) ^ (line & 7);
    aoff[mf] = line * 64 + chk * 8;
  }
#pragma unroll
  for (int nf = 0; nf < 4; ++nf) {
    int row = wn * 64 + nf * 16 + (l & 15);
    int line = row >> 1;
    int chk = (((row & 1) << 2) | (l >> 4)) ^ (line & 7);
    boff[nf] = line * 64 + chk * 8;
  }

  VMW0();

#define STAGE_A2(tt, Abuf) do {                                                       \
    gload16(hid + (size_t)(m0 + r0) * DIM + ((tt) << 5) + kc0, (Abuf) + adst0);       \
    gload16(hid + (size_t)(m0 + r1) * DIM + ((tt) << 5) + kc1, (Abuf) + adst1);       \
  } while (0)
#define STAGE_B2(tt, Bbuf) do {                                                       \
    gload16(w2t + (size_t)r0 * DIM + ((tt) << 5) + kc0, (Bbuf) + adst0);              \
    gload16(w2t + (size_t)r1 * DIM + ((tt) << 5) + kc1, (Bbuf) + adst1);              \
  } while (0)

  STAGE_A2(0, Aring);
  STAGE_B2(0, Bring);
  STAGE_A2(1, Aring + BUFE);
  STAGE_B2(1, Bring + BUFE);
  VMW4();
  BAR();

  f32x4 acc[8][4] = {};
  int cur = 0, nx2 = 2;

#pragma unroll 1
  for (int t = 0; t < NT2; ++t) {
    unsigned short* Ac = Aring + cur * BUFE;
    unsigned short* Bc = Bring + cur * BUFE;
    unsigned short* An = Aring + nx2 * BUFE;
    unsigned short* Bn = Bring + nx2 * BUFE;
    const int t2 = t + 2;
    const bool do_stage = (t2 < NT2);

    bf16x8 af[4], bfr[4];
#pragma unroll
    for (int mf = 0; mf < 4; ++mf) af[mf] = *(const bf16x8*)(Ac + aoff[mf]);
#pragma unroll
    for (int nf = 0; nf < 4; ++nf) bfr[nf] = *(const bf16x8*)(Bc + boff[nf]);
    if (do_stage) STAGE_A2(t2, An);
    BAR();
    LGKM0();
    __builtin_amdgcn_s_setprio(1);
#pragma unroll
    for (int mf = 0; mf < 4; ++mf)
#pragma unroll
      for (int nf = 0; nf < 4; ++nf)
        acc[mf][nf] = __builtin_amdgcn_mfma_f32_16x16x32_bf16(af[mf], bfr[nf], acc[mf][nf], 0, 0, 0);
    __builtin_amdgcn_s_setprio(0);
    BAR();

#pragma unroll
    for (int mf = 0; mf < 4; ++mf) af[mf] = *(const bf16x8*)(Ac + aoff[4 + mf]);
    if (do_stage) STAGE_B2(t2, Bn);
    BAR();
    LGKM0();
    __builtin_amdgcn_s_setprio(1);
#pragma unroll
    for (int mf = 0; mf < 4; ++mf)
#pragma unroll
      for (int nf = 0; nf < 4; ++nf)
        acc[4 + mf][nf] = __builtin_amdgcn_mfma_f32_16x16x32_bf16(af[mf], bfr[nf], acc[4 + mf][nf], 0, 0, 0);
    __builtin_amdgcn_s_setprio(0);
    if (t < NT2 - 2) { VMW4(); } else if (t == NT2 - 2) { VMW0(); }
    BAR();

    cur = (cur == 2) ? 0 : cur + 1;
    nx2 = (nx2 == 2) ? 0 : nx2 + 1;
  }

#pragma unroll
  for (int nf = 0; nf < 4; ++nf) {
    int gn = wn * 64 + nf * 16 + (l & 15);
    float bias = b2[gn];
#pragma unroll
    for (int mf = 0; mf < 8; ++mf) {
      int gr0 = m0 + wm * 128 + mf * 16 + (l >> 4) * 4;
#pragma unroll
      for (int q = 0; q < 4; ++q) {
        int gm = gr0 + q;
        if (gm < N_ABOVE) out[(size_t)gm * DIM + gn] = acc[mf][nf][q] + bias;
      }
    }
  }
#undef STAGE_A2
#undef STAGE_B2
}

extern "C" void kernel_launch(void* const* d_in, const int* in_sizes, int n_in,
                              void* d_out, int out_size, void* d_ws, size_t ws_size,
                              hipStream_t stream) {
  const float* h    = (const float*)d_in[0];
  const int*   idx  = (const int*)d_in[2];
  const int*   jarr = (const int*)d_in[4];
  const float* W1   = (const float*)d_in[5];
  const float* b1   = (const float*)d_in[6];
  const float* W2   = (const float*)d_in[7];
  const float* b2   = (const float*)d_in[8];
  float* out = (float*)d_out;

  char* ws = (char*)d_ws;
  size_t off = 0;
  auto alloc = [&](size_t bytes) -> void* {
    void* p = ws + off;
    off += bytes;
    off = (off + 511) & ~(size_t)511;
    return p;
  };
  int*            inv = (int*)alloc((size_t)N_ABOVE * 4);
  unsigned short* hbf = (unsigned short*)alloc((size_t)(N_DOWN + 1) * DIM * 2);
  unsigned short* w1t = (unsigned short*)alloc((size_t)DIM * K1 * 2);
  unsigned short* w2t = (unsigned short*)alloc((size_t)DIM * DIM * 2);
  unsigned short* hid = (unsigned short*)alloc((size_t)MPAD * DIM * 2);
  if (ws_size < off) return;

  k_prep_inv<<<dim3(391), dim3(256), 0, stream>>>(inv, hbf);
  k_scatter<<<dim3(196), dim3(256), 0, stream>>>(idx, inv);
  k_h2bf<<<dim3(12500), dim3(256), 0, stream>>>(h, hbf);
  k_transpose_bf<<<dim3(K1 / 64, DIM / 64), dim3(256), 0, stream>>>(W1, w1t, K1, DIM);
  k_transpose_bf<<<dim3(DIM / 64, DIM / 64), dim3(256), 0, stream>>>(W2, w2t, DIM, DIM);
  const size_t smem = (size_t)(6 * BUFE) * sizeof(unsigned short);  // 96 KiB
  k_gemm1<<<dim3(MPAD / 256), dim3(512), smem, stream>>>(hbf, w1t, b1, inv, jarr, hid);
  k_gemm2<<<dim3(MPAD / 256), dim3(512), smem, stream>>>(hid, w2t, b2, out);
}

// Round 4
// 158.380 us; speedup vs baseline: 1.0839x; 1.0839x over previous
//
#include <hip/hip_runtime.h>

#define N_DOWN  50000
#define N_ABOVE 100000
#define DIM     256
#define FAN     5
#define K1      1280      // FAN * DIM
#define MPAD    100096    // 782 * 128
#define NT1     40        // K1 / 32
#define NT2     8         // DIM / 32
#define ASLOT   4096      // 64 lines * 64 elems  (128 rows x 32 k) = 8 KiB
#define BSLOT   8192      // 128 lines * 64 elems (256 rows x 32 k) = 16 KiB

typedef __bf16 bf16x8 __attribute__((ext_vector_type(8)));
typedef float  f32x4  __attribute__((ext_vector_type(4)));

__device__ __forceinline__ unsigned short f2bf(float f) {
  unsigned u = __builtin_bit_cast(unsigned, f);
  u += 0x7FFFu + ((u >> 16) & 1u);          // RNE round to bf16
  return (unsigned short)(u >> 16);
}

__device__ __forceinline__ void gload16(const unsigned short* g, unsigned short* l) {
  __builtin_amdgcn_global_load_lds(
      (const __attribute__((address_space(1))) void*)g,
      (__attribute__((address_space(3))) void*)l, 16, 0, 0);
}

#define BAR()   __builtin_amdgcn_s_barrier()
#define SCB()   __builtin_amdgcn_sched_barrier(0)
#define LGKM4() do { asm volatile("s_waitcnt lgkmcnt(4)" ::: "memory"); SCB(); } while (0)
#define LGKM0() do { asm volatile("s_waitcnt lgkmcnt(0)" ::: "memory"); SCB(); } while (0)
#define VMW6()  do { asm volatile("s_waitcnt vmcnt(6)" ::: "memory"); SCB(); } while (0)
#define VMW0()  do { asm volatile("s_waitcnt vmcnt(0)" ::: "memory"); SCB(); } while (0)

// ---- prep ----
__global__ void k_prep_inv(int* __restrict__ inv, unsigned short* __restrict__ hbf) {
  int t = blockIdx.x * 256 + threadIdx.x;
  if (t < N_ABOVE) inv[t] = N_DOWN;                 // sentinel -> zero row
  if (t < DIM)     hbf[(size_t)N_DOWN * DIM + t] = 0;
}

__global__ void k_scatter(const int* __restrict__ idx, int* __restrict__ inv) {
  int t = blockIdx.x * 256 + threadIdx.x;
  if (t < N_DOWN) inv[idx[t]] = t;
}

__global__ void k_h2bf(const float* __restrict__ h, unsigned short* __restrict__ hbf) {
  int t = blockIdx.x * 256 + threadIdx.x;           // grid sized exactly: 12500*256
  float4 v = ((const float4*)h)[t];
  ushort4 o;
  o.x = f2bf(v.x); o.y = f2bf(v.y); o.z = f2bf(v.z); o.w = f2bf(v.w);
  ((ushort4*)hbf)[t] = o;
}

// in: [K][N] f32 row-major -> out: [N][K] bf16 row-major
__global__ void k_transpose_bf(const float* __restrict__ in, unsigned short* __restrict__ out,
                               int K, int N) {
  __shared__ float tile[64][65];
  int k0 = blockIdx.x * 64, n0 = blockIdx.y * 64;
  int c = threadIdx.x & 63, rb = threadIdx.x >> 6;
#pragma unroll
  for (int rr = 0; rr < 16; ++rr) {
    int row = rb + rr * 4;
    tile[row][c] = in[(size_t)(k0 + row) * N + n0 + c];
  }
  __syncthreads();
#pragma unroll
  for (int rr = 0; rr < 16; ++rr) {
    int nr = rb + rr * 4;
    out[(size_t)(n0 + nr) * K + k0 + c] = f2bf(tile[c][nr]);
  }
}

// LDS pair-row layout (verified R3: 0 bank conflicts, correct):
//   elem (row r, k) at line=r>>1, chunk=(((r&1)<<2)|(k>>3))^(line&7), e=k&7.
//   Staging lane-linear: lane l writes chunk l&7 of line base+(l>>3); inverse-
//   swizzled global source row = 2*line + (u>>2), kc=(u&3)*8, u=(l&7)^(l>>3).

// ---- GEMM1 (128x256, 4 waves, ring-3, pipelined reads): hid = relu(gather@W1+b1)
__global__ __launch_bounds__(256, 2) void k_gemm1(
    const unsigned short* __restrict__ hbf,   // [N_DOWN+1][256] bf16
    const unsigned short* __restrict__ w1t,   // [256][1280]  bf16 (W1^T)
    const float* __restrict__ b1,
    const int* __restrict__ inv,              // [N_ABOVE]
    const int* __restrict__ jarr,             // [N_ABOVE*FAN]
    unsigned short* __restrict__ hid)         // [MPAD][256] bf16
{
  extern __shared__ __align__(16) unsigned short smem[];
  unsigned short* Aring = smem;               // 3 * ASLOT
  unsigned short* Bring = smem + 3 * ASLOT;   // 3 * BSLOT

  const int tid = threadIdx.x;
  const int w = tid >> 6, l = tid & 63;
  const int m0 = blockIdx.x * 128;

  // staging geometry
  const int u  = (l & 7) ^ (l >> 3);
  const int kc = (u & 3) * 8;
  const int rh = 2 * (l >> 3) + (u >> 2);
  const int rA0 = w * 32 + rh;                // A rows this thread stages
  const int rA1 = rA0 + 16;
  const int rB0 = w * 64 + rh;                // B rows
  const int rB1 = rB0 + 16, rB2 = rB0 + 32, rB3 = rB0 + 48;
  const int dA0 = w * 1024, dA1 = dA0 + 512;  // LDS elem bases (wave-uniform)
  const int dB0 = w * 2048, dB1 = dB0 + 512, dB2 = dB0 + 1024, dB3 = dB0 + 1536;

  // gather sources for my 2 A-rows, 5 segments (named regs, static)
  const int gm0 = min(m0 + rA0, N_ABOVE - 1);
  const int gm1 = min(m0 + rA1, N_ABOVE - 1);
  const int s00 = inv[jarr[(size_t)gm0 * FAN + 0]], s01 = inv[jarr[(size_t)gm0 * FAN + 1]],
            s02 = inv[jarr[(size_t)gm0 * FAN + 2]], s03 = inv[jarr[(size_t)gm0 * FAN + 3]],
            s04 = inv[jarr[(size_t)gm0 * FAN + 4]];
  const int s10 = inv[jarr[(size_t)gm1 * FAN + 0]], s11 = inv[jarr[(size_t)gm1 * FAN + 1]],
            s12 = inv[jarr[(size_t)gm1 * FAN + 2]], s13 = inv[jarr[(size_t)gm1 * FAN + 3]],
            s14 = inv[jarr[(size_t)gm1 * FAN + 4]];

  // fragment read offsets (t-invariant)
  int aoff[8], boff[4];
#pragma unroll
  for (int mf = 0; mf < 8; ++mf) {
    int row = mf * 16 + (l & 15);             // per-wave A covers all 128 rows
    int line = row >> 1;
    int chk = (((row & 1) << 2) | (l >> 4)) ^ (line & 7);
    aoff[mf] = line * 64 + chk * 8;
  }
#pragma unroll
  for (int nf = 0; nf < 4; ++nf) {
    int row = w * 64 + nf * 16 + (l & 15);    // wave n-slice
    int line = row >> 1;
    int chk = (((row & 1) << 2) | (l >> 4)) ^ (line & 7);
    boff[nf] = line * 64 + chk * 8;
  }

  VMW0();   // retire gather loads: clean VMEM FIFO for counted staging

#define STAGE1(tt, Ab, Bb, S0, S1) do {                                            \
    gload16(hbf + ((size_t)(S0) << 8) + (((tt) & 7) << 5) + kc, (Ab) + dA0);       \
    gload16(hbf + ((size_t)(S1) << 8) + (((tt) & 7) << 5) + kc, (Ab) + dA1);       \
    gload16(w1t + (size_t)rB0 * K1 + ((tt) << 5) + kc, (Bb) + dB0);                \
    gload16(w1t + (size_t)rB1 * K1 + ((tt) << 5) + kc, (Bb) + dB1);                \
    gload16(w1t + (size_t)rB2 * K1 + ((tt) << 5) + kc, (Bb) + dB2);                \
    gload16(w1t + (size_t)rB3 * K1 + ((tt) << 5) + kc, (Bb) + dB3);                \
  } while (0)

  bf16x8 af[8], bfr[4];
#define READ12(Ab, Bb) do {                                                        \
    af[0] = *(const bf16x8*)((Ab) + aoff[0]);                                      \
    af[1] = *(const bf16x8*)((Ab) + aoff[1]);                                      \
    af[2] = *(const bf16x8*)((Ab) + aoff[2]);                                      \
    af[3] = *(const bf16x8*)((Ab) + aoff[3]);                                      \
    bfr[0] = *(const bf16x8*)((Bb) + boff[0]);                                     \
    bfr[1] = *(const bf16x8*)((Bb) + boff[1]);                                     \
    bfr[2] = *(const bf16x8*)((Bb) + boff[2]);                                     \
    bfr[3] = *(const bf16x8*)((Bb) + boff[3]);                                     \
    SCB();                                                                         \
    af[4] = *(const bf16x8*)((Ab) + aoff[4]);                                      \
    af[5] = *(const bf16x8*)((Ab) + aoff[5]);                                      \
    af[6] = *(const bf16x8*)((Ab) + aoff[6]);                                      \
    af[7] = *(const bf16x8*)((Ab) + aoff[7]);                                      \
    SCB();                                                                         \
  } while (0)

  // prologue: stage tiles 0,1 (segment 0); read tile 0 fragments
  STAGE1(0, Aring, Bring, s00, s10);
  STAGE1(1, Aring + ASLOT, Bring + BSLOT, s00, s10);
  VMW6();                                     // tile 0 landed (tile 1 in flight)
  BAR();
  READ12(Aring, Bring);

  f32x4 acc[8][4] = {};
  int ic = 0;                                 // current buf
#pragma unroll 1
  for (int t = 0; t < NT1; ++t) {
    const int t2 = t + 2;
    if (t2 < NT1) {
      const int is = (ic == 0) ? 2 : ic - 1;  // (ic+2)%3
      const int seg = t2 >> 3;
      const int ss0 = seg == 0 ? s00 : seg == 1 ? s01 : seg == 2 ? s02 : seg == 3 ? s03 : s04;
      const int ss1 = seg == 0 ? s10 : seg == 1 ? s11 : seg == 2 ? s12 : seg == 3 ? s13 : s14;
      STAGE1(t2, Aring + is * ASLOT, Bring + is * BSLOT, ss0, ss1);
    }
    LGKM4();                                  // af[0..3], bfr[0..3] ready
    __builtin_amdgcn_s_setprio(1);
#pragma unroll
    for (int mf = 0; mf < 4; ++mf)
#pragma unroll
      for (int nf = 0; nf < 4; ++nf)
        acc[mf][nf] = __builtin_amdgcn_mfma_f32_16x16x32_bf16(af[mf], bfr[nf], acc[mf][nf], 0, 0, 0);
    __builtin_amdgcn_s_setprio(0);
    LGKM0();                                  // af[4..7] ready (hid under cluster 1)
    __builtin_amdgcn_s_setprio(1);
#pragma unroll
    for (int mf = 0; mf < 4; ++mf)
#pragma unroll
      for (int nf = 0; nf < 4; ++nf)
        acc[4 + mf][nf] = __builtin_amdgcn_mfma_f32_16x16x32_bf16(af[4 + mf], bfr[nf], acc[4 + mf][nf], 0, 0, 0);
    __builtin_amdgcn_s_setprio(0);
    if (t < NT1 - 2) { VMW6(); } else if (t == NT1 - 2) { VMW0(); }
    BAR();                                    // tile t+1 LDS valid block-wide
    const int in_ = (ic == 2) ? 0 : ic + 1;   // (ic+1)%3
    READ12(Aring + in_ * ASLOT, Bring + in_ * BSLOT);  // stale on last iter: unused
    ic = in_;
  }

  // epilogue: bias + relu -> bf16
#pragma unroll
  for (int nf = 0; nf < 4; ++nf) {
    int gn = w * 64 + nf * 16 + (l & 15);
    float bias = b1[gn];
#pragma unroll
    for (int mf = 0; mf < 8; ++mf) {
      int gr0 = m0 + mf * 16 + (l >> 4) * 4;
#pragma unroll
      for (int q = 0; q < 4; ++q) {
        float v = acc[mf][nf][q] + bias;
        v = v > 0.f ? v : 0.f;
        hid[(size_t)(gr0 + q) * DIM + gn] = f2bf(v);
      }
    }
  }
#undef STAGE1
#undef READ12
}

// ---- GEMM2 (same structure, no gather, NT=8): out = hid @ W2 + b2 (f32) ----
__global__ __launch_bounds__(256, 2) void k_gemm2(
    const unsigned short* __restrict__ hid,   // [MPAD][256] bf16
    const unsigned short* __restrict__ w2t,   // [256][256] bf16 (W2^T)
    const float* __restrict__ b2,
    float* __restrict__ out)
{
  extern __shared__ __align__(16) unsigned short smem[];
  unsigned short* Aring = smem;
  unsigned short* Bring = smem + 3 * ASLOT;

  const int tid = threadIdx.x;
  const int w = tid >> 6, l = tid & 63;
  const int m0 = blockIdx.x * 128;

  const int u  = (l & 7) ^ (l >> 3);
  const int kc = (u & 3) * 8;
  const int rh = 2 * (l >> 3) + (u >> 2);
  const int rA0 = w * 32 + rh, rA1 = rA0 + 16;
  const int rB0 = w * 64 + rh;
  const int rB1 = rB0 + 16, rB2 = rB0 + 32, rB3 = rB0 + 48;
  const int dA0 = w * 1024, dA1 = dA0 + 512;
  const int dB0 = w * 2048, dB1 = dB0 + 512, dB2 = dB0 + 1024, dB3 = dB0 + 1536;

  int aoff[8], boff[4];
#pragma unroll
  for (int mf = 0; mf < 8; ++mf) {
    int row = mf * 16 + (l & 15);
    int line = row >> 1;
    int chk = (((row & 1) << 2) | (l >> 4)) ^ (line & 7);
    aoff[mf] = line * 64 + chk * 8;
  }
#pragma unroll
  for (int nf = 0; nf < 4; ++nf) {
    int row = w * 64 + nf * 16 + (l & 15);
    int line = row >> 1;
    int chk = (((row & 1) << 2) | (l >> 4)) ^ (line & 7);
    boff[nf] = line * 64 + chk * 8;
  }

  VMW0();

#define STAGE2(tt, Ab, Bb) do {                                                    \
    gload16(hid + (size_t)(m0 + rA0) * DIM + ((tt) << 5) + kc, (Ab) + dA0);        \
    gload16(hid + (size_t)(m0 + rA1) * DIM + ((tt) << 5) + kc, (Ab) + dA1);        \
    gload16(w2t + (size_t)rB0 * DIM + ((tt) << 5) + kc, (Bb) + dB0);               \
    gload16(w2t + (size_t)rB1 * DIM + ((tt) << 5) + kc, (Bb) + dB1);               \
    gload16(w2t + (size_t)rB2 * DIM + ((tt) << 5) + kc, (Bb) + dB2);               \
    gload16(w2t + (size_t)rB3 * DIM + ((tt) << 5) + kc, (Bb) + dB3);               \
  } while (0)

  bf16x8 af[8], bfr[4];
#define READ12(Ab, Bb) do {                                                        \
    af[0] = *(const bf16x8*)((Ab) + aoff[0]);                                      \
    af[1] = *(const bf16x8*)((Ab) + aoff[1]);                                      \
    af[2] = *(const bf16x8*)((Ab) + aoff[2]);                                      \
    af[3] = *(const bf16x8*)((Ab) + aoff[3]);                                      \
    bfr[0] = *(const bf16x8*)((Bb) + boff[0]);                                     \
    bfr[1] = *(const bf16x8*)((Bb) + boff[1]);                                     \
    bfr[2] = *(const bf16x8*)((Bb) + boff[2]);                                     \
    bfr[3] = *(const bf16x8*)((Bb) + boff[3]);                                     \
    SCB();                                                                         \
    af[4] = *(const bf16x8*)((Ab) + aoff[4]);                                      \
    af[5] = *(const bf16x8*)((Ab) + aoff[5]);                                      \
    af[6] = *(const bf16x8*)((Ab) + aoff[6]);                                      \
    af[7] = *(const bf16x8*)((Ab) + aoff[7]);                                      \
    SCB();                                                                         \
  } while (0)

  STAGE2(0, Aring, Bring);
  STAGE2(1, Aring + ASLOT, Bring + BSLOT);
  VMW6();
  BAR();
  READ12(Aring, Bring);

  f32x4 acc[8][4] = {};
  int ic = 0;
#pragma unroll 1
  for (int t = 0; t < NT2; ++t) {
    const int t2 = t + 2;
    if (t2 < NT2) {
      const int is = (ic == 0) ? 2 : ic - 1;
      STAGE2(t2, Aring + is * ASLOT, Bring + is * BSLOT);
    }
    LGKM4();
    __builtin_amdgcn_s_setprio(1);
#pragma unroll
    for (int mf = 0; mf < 4; ++mf)
#pragma unroll
      for (int nf = 0; nf < 4; ++nf)
        acc[mf][nf] = __builtin_amdgcn_mfma_f32_16x16x32_bf16(af[mf], bfr[nf], acc[mf][nf], 0, 0, 0);
    __builtin_amdgcn_s_setprio(0);
    LGKM0();
    __builtin_amdgcn_s_setprio(1);
#pragma unroll
    for (int mf = 0; mf < 4; ++mf)
#pragma unroll
      for (int nf = 0; nf < 4; ++nf)
        acc[4 + mf][nf] = __builtin_amdgcn_mfma_f32_16x16x32_bf16(af[4 + mf], bfr[nf], acc[4 + mf][nf], 0, 0, 0);
    __builtin_amdgcn_s_setprio(0);
    if (t < NT2 - 2) { VMW6(); } else if (t == NT2 - 2) { VMW0(); }
    BAR();
    const int in_ = (ic == 2) ? 0 : ic + 1;
    READ12(Aring + in_ * ASLOT, Bring + in_ * BSLOT);
    ic = in_;
  }

#pragma unroll
  for (int nf = 0; nf < 4; ++nf) {
    int gn = w * 64 + nf * 16 + (l & 15);
    float bias = b2[gn];
#pragma unroll
    for (int mf = 0; mf < 8; ++mf) {
      int gr0 = m0 + mf * 16 + (l >> 4) * 4;
#pragma unroll
      for (int q = 0; q < 4; ++q) {
        int gm = gr0 + q;
        if (gm < N_ABOVE) out[(size_t)gm * DIM + gn] = acc[mf][nf][q] + bias;
      }
    }
  }
#undef STAGE2
#undef READ12
}

extern "C" void kernel_launch(void* const* d_in, const int* in_sizes, int n_in,
                              void* d_out, int out_size, void* d_ws, size_t ws_size,
                              hipStream_t stream) {
  const float* h    = (const float*)d_in[0];
  const int*   idx  = (const int*)d_in[2];
  const int*   jarr = (const int*)d_in[4];
  const float* W1   = (const float*)d_in[5];
  const float* b1   = (const float*)d_in[6];
  const float* W2   = (const float*)d_in[7];
  const float* b2   = (const float*)d_in[8];
  float* out = (float*)d_out;

  char* ws = (char*)d_ws;
  size_t off = 0;
  auto alloc = [&](size_t bytes) -> void* {
    void* p = ws + off;
    off += bytes;
    off = (off + 511) & ~(size_t)511;
    return p;
  };
  int*            inv = (int*)alloc((size_t)N_ABOVE * 4);
  unsigned short* hbf = (unsigned short*)alloc((size_t)(N_DOWN + 1) * DIM * 2);
  unsigned short* w1t = (unsigned short*)alloc((size_t)DIM * K1 * 2);
  unsigned short* w2t = (unsigned short*)alloc((size_t)DIM * DIM * 2);
  unsigned short* hid = (unsigned short*)alloc((size_t)MPAD * DIM * 2);
  if (ws_size < off) return;

  k_prep_inv<<<dim3(391), dim3(256), 0, stream>>>(inv, hbf);
  k_scatter<<<dim3(196), dim3(256), 0, stream>>>(idx, inv);
  k_h2bf<<<dim3(12500), dim3(256), 0, stream>>>(h, hbf);
  k_transpose_bf<<<dim3(K1 / 64, DIM / 64), dim3(256), 0, stream>>>(W1, w1t, K1, DIM);
  k_transpose_bf<<<dim3(DIM / 64, DIM / 64), dim3(256), 0, stream>>>(W2, w2t, DIM, DIM);
  const size_t smem = (size_t)(3 * ASLOT + 3 * BSLOT) * sizeof(unsigned short); // 72 KiB
  k_gemm1<<<dim3(MPAD / 128), dim3(256), smem, stream>>>(hbf, w1t, b1, inv, jarr, hid);
  k_gemm2<<<dim3(MPAD / 128), dim3(256), smem, stream>>>(hid, w2t, b2, out);
}

// Round 5
// 146.637 us; speedup vs baseline: 1.1707x; 1.0801x over previous
//
#include <hip/hip_runtime.h>

#define N_DOWN  50000
#define N_ABOVE 100000
#define DIM     256
#define FAN     5
#define K1      1280      // FAN * DIM
#define MPAD    100096    // 782 * 128

typedef __bf16 bf16x8 __attribute__((ext_vector_type(8)));
typedef float  f32x4  __attribute__((ext_vector_type(4)));

__device__ __forceinline__ unsigned short f2bf(float f) {
  unsigned u = __builtin_bit_cast(unsigned, f);
  u += 0x7FFFu + ((u >> 16) & 1u);          // RNE round to bf16
  return (unsigned short)(u >> 16);
}

__device__ __forceinline__ void gload16(const unsigned short* g, unsigned short* l) {
  __builtin_amdgcn_global_load_lds(
      (const __attribute__((address_space(1))) void*)g,
      (__attribute__((address_space(3))) void*)l, 16, 0, 0);
}

// ---- prep ----
__global__ void k_prep_inv(int* __restrict__ inv, unsigned short* __restrict__ hbf) {
  int t = blockIdx.x * 256 + threadIdx.x;
  if (t < N_ABOVE) inv[t] = N_DOWN;                 // sentinel -> zero row
  if (t < DIM)     hbf[(size_t)N_DOWN * DIM + t] = 0;
}

__global__ void k_scatter(const int* __restrict__ idx, int* __restrict__ inv) {
  int t = blockIdx.x * 256 + threadIdx.x;
  if (t < N_DOWN) inv[idx[t]] = t;
}

__global__ void k_h2bf(const float* __restrict__ h, unsigned short* __restrict__ hbf) {
  int t = blockIdx.x * 256 + threadIdx.x;           // grid sized exactly: 12500*256
  float4 v = ((const float4*)h)[t];
  ushort4 o;
  o.x = f2bf(v.x); o.y = f2bf(v.y); o.z = f2bf(v.z); o.w = f2bf(v.w);
  ((ushort4*)hbf)[t] = o;
}

// in: [K][N] f32 row-major -> out: [N][K] bf16 row-major
__global__ void k_transpose_bf(const float* __restrict__ in, unsigned short* __restrict__ out,
                               int K, int N) {
  __shared__ float tile[64][65];
  int k0 = blockIdx.x * 64, n0 = blockIdx.y * 64;
  int c = threadIdx.x & 63, rb = threadIdx.x >> 6;
#pragma unroll
  for (int rr = 0; rr < 16; ++rr) {
    int row = rb + rr * 4;
    tile[row][c] = in[(size_t)(k0 + row) * N + n0 + c];
  }
  __syncthreads();
#pragma unroll
  for (int rr = 0; rr < 16; ++rr) {
    int nr = rb + rr * 4;
    out[(size_t)(n0 + nr) * K + k0 + c] = f2bf(tile[c][nr]);
  }
}

// ---- fused: out = relu(gather(hbf)@W1 + b1) @ W2 + b2 ----
// BM=128, BN=256 (full), 512 thr = 8 waves (2M x 4N), per-wave 64x64 (R1 config).
// GEMM1: R1's proven 2-barrier K-loop, XOR-swizzled global_load_lds staging.
// GEMM2: hid in LDS (64 KB, aliases staging), B-frags direct from L2-resident W2T.
__global__ __launch_bounds__(512, 4) void k_fused(
    const unsigned short* __restrict__ hbf,   // [N_DOWN+1][256] bf16
    const unsigned short* __restrict__ w1t,   // [256][1280]  bf16 (W1^T)
    const float* __restrict__ b1,
    const unsigned short* __restrict__ w2t,   // [256][256] bf16 (W2^T)
    const float* __restrict__ b2,
    const int* __restrict__ inv,              // [N_ABOVE]
    const int* __restrict__ jarr,             // [N_ABOVE*FAN]
    float* __restrict__ out)                  // [N_ABOVE][256] f32
{
  extern __shared__ __align__(16) unsigned short smem[];
  unsigned short* Alds = smem;                       // [128*64]  16 KB
  unsigned short* Blds = smem + 128 * 64;            // [256*64]  32 KB
  int* srcrow = (int*)(smem + 128 * 64 + 256 * 64);  // 640 ints @48..50.5 KB
  unsigned short* hid_lds = smem;                    // [128*256] 64 KB (aliases all)

  const int tid = threadIdx.x;
  const int w = tid >> 6, l = tid & 63;
  const int m0 = blockIdx.x * 128;
  const int wm = w >> 2, wn = w & 3;          // 2M x 4N waves, 64x64 each
  const int srow = l >> 3, slot = l & 7;

  // per-block gather table: srcrow[row*FAN+r] = hbf row feeding segment r
  for (int e = tid; e < 128 * FAN; e += 512) {
    int row = e / FAN, rr = e - row * FAN;
    int gm = m0 + row;
    int s = N_DOWN;
    if (gm < N_ABOVE) s = inv[jarr[(size_t)gm * FAN + rr]];
    srcrow[e] = s;
  }

  f32x4 acc[4][4] = {};

  // ---------------- GEMM1 main loop (R1 structure) ----------------
  for (int t = 0; t < 20; ++t) {
    const int r = t >> 2;                     // fan-in segment
    __syncthreads();                          // prev compute done; srcrow visible (t=0)
#pragma unroll
    for (int i = 0; i < 2; ++i) {             // stage A: 128 rows x 64k
      int row = w * 16 + i * 8 + srow;
      int src = srcrow[row * FAN + r];
      int c = slot ^ (row & 7);
      gload16(hbf + ((size_t)src << 8) + ((t & 3) << 6) + (c << 3),
              Alds + (w * 16 + i * 8) * 64);
    }
#pragma unroll
    for (int i = 0; i < 4; ++i) {             // stage B: 256 rows x 64k
      int row = w * 32 + i * 8 + srow;
      int c = slot ^ (row & 7);
      gload16(w1t + (size_t)row * K1 + (t << 6) + (c << 3),
              Blds + (w * 32 + i * 8) * 64);
    }
    __syncthreads();                          // compiler drains vmcnt before barrier

#pragma unroll
    for (int kk = 0; kk < 2; ++kk) {
      bf16x8 af[4], bfr[4];
#pragma unroll
      for (int m = 0; m < 4; ++m) {
        int row = wm * 64 + m * 16 + (l & 15);
        int c = (kk * 4 + (l >> 4)) ^ (row & 7);
        af[m] = *(const bf16x8*)(Alds + row * 64 + c * 8);
      }
#pragma unroll
      for (int n = 0; n < 4; ++n) {
        int row = wn * 64 + n * 16 + (l & 15);
        int c = (kk * 4 + (l >> 4)) ^ (row & 7);
        bfr[n] = *(const bf16x8*)(Blds + row * 64 + c * 8);
      }
#pragma unroll
      for (int m = 0; m < 4; ++m)
#pragma unroll
        for (int n = 0; n < 4; ++n)
          acc[m][n] = __builtin_amdgcn_mfma_f32_16x16x32_bf16(af[m], bfr[n], acc[m][n], 0, 0, 0);
    }
  }
  __syncthreads();                            // all GEMM1 LDS reads done block-wide

  // ---------------- hid -> LDS (relu + bias, bf16, swizzled chunks) ----------------
#pragma unroll
  for (int nf = 0; nf < 4; ++nf) {
    int col = wn * 64 + nf * 16 + (l & 15);
    float bias = b1[col];
#pragma unroll
    for (int mf = 0; mf < 4; ++mf) {
#pragma unroll
      for (int q = 0; q < 4; ++q) {
        int row = wm * 64 + mf * 16 + (l >> 4) * 4 + q;
        float v = acc[mf][nf][q] + bias;
        v = v > 0.f ? v : 0.f;
        hid_lds[row * 256 + (((col >> 3) ^ (row & 7)) << 3) + (col & 7)] = f2bf(v);
      }
    }
  }
  __syncthreads();

  // ---------------- GEMM2: out_tile = hid_lds @ W2 + b2 (no barriers) ----------------
  f32x4 acc2[4][4] = {};
#pragma unroll 1
  for (int t2 = 0; t2 < 8; ++t2) {
    bf16x8 af2[4], bf2[4];
#pragma unroll
    for (int nf = 0; nf < 4; ++nf) {          // B direct from L2-resident W2T
      int nr = wn * 64 + nf * 16 + (l & 15);
      bf2[nf] = *(const bf16x8*)(w2t + (size_t)nr * DIM + t2 * 32 + ((l >> 4) << 3));
    }
#pragma unroll
    for (int mf = 0; mf < 4; ++mf) {          // A from hid_lds (swizzled)
      int row = wm * 64 + mf * 16 + (l & 15);
      int g = t2 * 4 + (l >> 4);
      af2[mf] = *(const bf16x8*)(hid_lds + row * 256 + ((g ^ (row & 7)) << 3));
    }
#pragma unroll
    for (int mf = 0; mf < 4; ++mf)
#pragma unroll
      for (int nf = 0; nf < 4; ++nf)
        acc2[mf][nf] = __builtin_amdgcn_mfma_f32_16x16x32_bf16(af2[mf], bf2[nf], acc2[mf][nf], 0, 0, 0);
  }

  // epilogue: bias -> f32 out
#pragma unroll
  for (int nf = 0; nf < 4; ++nf) {
    int gn = wn * 64 + nf * 16 + (l & 15);
    float bias = b2[gn];
#pragma unroll
    for (int mf = 0; mf < 4; ++mf) {
      int gr0 = m0 + wm * 64 + mf * 16 + (l >> 4) * 4;
#pragma unroll
      for (int q = 0; q < 4; ++q) {
        int gm = gr0 + q;
        if (gm < N_ABOVE) out[(size_t)gm * DIM + gn] = acc2[mf][nf][q] + bias;
      }
    }
  }
}

extern "C" void kernel_launch(void* const* d_in, const int* in_sizes, int n_in,
                              void* d_out, int out_size, void* d_ws, size_t ws_size,
                              hipStream_t stream) {
  const float* h    = (const float*)d_in[0];
  const int*   idx  = (const int*)d_in[2];
  const int*   jarr = (const int*)d_in[4];
  const float* W1   = (const float*)d_in[5];
  const float* b1   = (const float*)d_in[6];
  const float* W2   = (const float*)d_in[7];
  const float* b2   = (const float*)d_in[8];
  float* out = (float*)d_out;

  char* ws = (char*)d_ws;
  size_t off = 0;
  auto alloc = [&](size_t bytes) -> void* {
    void* p = ws + off;
    off += bytes;
    off = (off + 511) & ~(size_t)511;
    return p;
  };
  int*            inv = (int*)alloc((size_t)N_ABOVE * 4);
  unsigned short* hbf = (unsigned short*)alloc((size_t)(N_DOWN + 1) * DIM * 2);
  unsigned short* w1t = (unsigned short*)alloc((size_t)DIM * K1 * 2);
  unsigned short* w2t = (unsigned short*)alloc((size_t)DIM * DIM * 2);
  if (ws_size < off) return;

  k_prep_inv<<<dim3(391), dim3(256), 0, stream>>>(inv, hbf);
  k_scatter<<<dim3(196), dim3(256), 0, stream>>>(idx, inv);
  k_h2bf<<<dim3(12500), dim3(256), 0, stream>>>(h, hbf);
  k_transpose_bf<<<dim3(K1 / 64, DIM / 64), dim3(256), 0, stream>>>(W1, w1t, K1, DIM);
  k_transpose_bf<<<dim3(DIM / 64, DIM / 64), dim3(256), 0, stream>>>(W2, w2t, DIM, DIM);
  const size_t smem = 65536;                  // 64 KiB: staging+srcrow aliased by hid_lds
  k_fused<<<dim3(MPAD / 128), dim3(512), smem, stream>>>(hbf, w1t, b1, w2t, b2, inv, jarr, out);
}

// Round 6
// 124.402 us; speedup vs baseline: 1.3799x; 1.1787x over previous
//
#include <hip/hip_runtime.h>

#define N_DOWN  50000
#define N_ABOVE 100000
#define DIM     256
#define FAN     5
#define K1      1280      // FAN * DIM
#define MPAD    100096    // 782 * 128

typedef __bf16 bf16x8 __attribute__((ext_vector_type(8)));
typedef float  f32x4  __attribute__((ext_vector_type(4)));

__device__ __forceinline__ unsigned short f2bf(float f) {
  unsigned u = __builtin_bit_cast(unsigned, f);
  u += 0x7FFFu + ((u >> 16) & 1u);          // RNE round to bf16
  return (unsigned short)(u >> 16);
}

__device__ __forceinline__ void gload16(const unsigned short* g, unsigned short* l) {
  __builtin_amdgcn_global_load_lds(
      (const __attribute__((address_space(1))) void*)g,
      (__attribute__((address_space(3))) void*)l, 16, 0, 0);
}

// ---- prep 1: inv sentinel + zero row (must precede scatter) ----
__global__ void k_prep_inv(int* __restrict__ inv, unsigned short* __restrict__ hbf) {
  int t = blockIdx.x * 256 + threadIdx.x;
  if (t < N_ABOVE) inv[t] = N_DOWN;                 // sentinel -> zero row
  if (t < DIM)     hbf[(size_t)N_DOWN * DIM + t] = 0;
}

// ---- prep 2: h->bf16 convert + scatter + W1T/W2T transposes, one kernel ----
// blocks [0,12500): h2bf; [12500,12696): scatter; [12696,12776): W1T; [12776,12792): W2T
__device__ __forceinline__ void transpose_tile(const float* __restrict__ in,
                                               unsigned short* __restrict__ out,
                                               int K, int N, int k0, int n0,
                                               float (*tile)[65]) {
  int c = threadIdx.x & 63, rb = threadIdx.x >> 6;
#pragma unroll
  for (int rr = 0; rr < 16; ++rr) {
    int row = rb + rr * 4;
    tile[row][c] = in[(size_t)(k0 + row) * N + n0 + c];
  }
  __syncthreads();
#pragma unroll
  for (int rr = 0; rr < 16; ++rr) {
    int nr = rb + rr * 4;
    out[(size_t)(n0 + nr) * K + k0 + c] = f2bf(tile[c][nr]);
  }
}

__global__ void k_prep_all(const float* __restrict__ h, const int* __restrict__ idx,
                           const float* __restrict__ W1, const float* __restrict__ W2,
                           int* __restrict__ inv, unsigned short* __restrict__ hbf,
                           unsigned short* __restrict__ w1t, unsigned short* __restrict__ w2t) {
  __shared__ float tile[64][65];
  const int b = blockIdx.x;
  if (b < 12500) {
    int t = b * 256 + threadIdx.x;                  // exactly 50000*256/4 float4s
    float4 v = ((const float4*)h)[t];
    ushort4 o;
    o.x = f2bf(v.x); o.y = f2bf(v.y); o.z = f2bf(v.z); o.w = f2bf(v.w);
    ((ushort4*)hbf)[t] = o;
  } else if (b < 12696) {
    int t = (b - 12500) * 256 + threadIdx.x;
    if (t < N_DOWN) inv[idx[t]] = t;
  } else if (b < 12776) {
    int bb = b - 12696;                             // 80 blocks: 20 k-tiles x 4 n-tiles
    transpose_tile(W1, w1t, K1, DIM, (bb % 20) * 64, (bb / 20) * 64, tile);
  } else {
    int bb = b - 12776;                             // 16 blocks: 4 x 4
    transpose_tile(W2, w2t, DIM, DIM, (bb % 4) * 64, (bb / 4) * 64, tile);
  }
}

// ---- GEMM1 (R1-verbatim structure): hid = relu(gather(hbf) @ W1 + b1) ----
__global__ __launch_bounds__(256, 2) void k_gemm1(
    const unsigned short* __restrict__ hbf,   // [N_DOWN+1][256] bf16
    const unsigned short* __restrict__ w1t,   // [256][1280]  bf16 (W1^T)
    const float* __restrict__ b1,
    const int* __restrict__ inv,              // [N_ABOVE]
    const int* __restrict__ jarr,             // [N_ABOVE*FAN]
    unsigned short* __restrict__ hid)         // [MPAD][256] bf16
{
  __shared__ __align__(16) unsigned short Alds[128 * 64];
  __shared__ __align__(16) unsigned short Blds[128 * 64];
  __shared__ int srcrow[128 * FAN];

  const int tid = threadIdx.x;
  const int w = tid >> 6, l = tid & 63;
  const int m0 = blockIdx.x * 128, n0 = blockIdx.y * 128;
  const int wm = w >> 1, wn = w & 1;
  const int srow = l >> 3, slot = l & 7;

  for (int e = tid; e < 128 * FAN; e += 256) {
    int row = e / FAN, rr = e - row * FAN;
    int gm = m0 + row;
    int s = N_DOWN;
    if (gm < N_ABOVE) s = inv[jarr[(size_t)gm * FAN + rr]];
    srcrow[e] = s;
  }

  f32x4 acc[4][4] = {};

  for (int t = 0; t < 20; ++t) {
    const int r = t >> 2;                      // fan-in segment
    __syncthreads();
#pragma unroll
    for (int i = 0; i < 4; ++i) {
      int row = w * 32 + i * 8 + srow;
      int src = srcrow[row * FAN + r];
      int c = slot ^ (row & 7);
      gload16(hbf + ((size_t)src << 8) + ((t & 3) << 6) + (c << 3),
              Alds + (w * 32 + i * 8) * 64);
    }
#pragma unroll
    for (int i = 0; i < 4; ++i) {
      int row = w * 32 + i * 8 + srow;
      int c = slot ^ (row & 7);
      gload16(w1t + (size_t)(n0 + row) * K1 + (t << 6) + (c << 3),
              Blds + (w * 32 + i * 8) * 64);
    }
    __syncthreads();

#pragma unroll
    for (int kk = 0; kk < 2; ++kk) {
      bf16x8 af[4], bfr[4];
#pragma unroll
      for (int m = 0; m < 4; ++m) {
        int row = wm * 64 + m * 16 + (l & 15);
        int c = (kk * 4 + (l >> 4)) ^ (row & 7);
        af[m] = *(const bf16x8*)(Alds + row * 64 + c * 8);
      }
#pragma unroll
      for (int n = 0; n < 4; ++n) {
        int row = wn * 64 + n * 16 + (l & 15);
        int c = (kk * 4 + (l >> 4)) ^ (row & 7);
        bfr[n] = *(const bf16x8*)(Blds + row * 64 + c * 8);
      }
#pragma unroll
      for (int m = 0; m < 4; ++m)
#pragma unroll
        for (int n = 0; n < 4; ++n)
          acc[m][n] = __builtin_amdgcn_mfma_f32_16x16x32_bf16(af[m], bfr[n], acc[m][n], 0, 0, 0);
    }
  }

  // epilogue: bias + relu -> bf16; nf innermost => 128B contiguous per 16-lane group
  float bias0 = b1[n0 + wn * 64 + 0 * 16 + (l & 15)];
  float bias1 = b1[n0 + wn * 64 + 1 * 16 + (l & 15)];
  float bias2 = b1[n0 + wn * 64 + 2 * 16 + (l & 15)];
  float bias3 = b1[n0 + wn * 64 + 3 * 16 + (l & 15)];
#pragma unroll
  for (int m = 0; m < 4; ++m) {
#pragma unroll
    for (int q = 0; q < 4; ++q) {
      int gm = m0 + wm * 64 + m * 16 + (l >> 4) * 4 + q;
#pragma unroll
      for (int n = 0; n < 4; ++n) {
        float bias = n == 0 ? bias0 : n == 1 ? bias1 : n == 2 ? bias2 : bias3;
        int gn = n0 + wn * 64 + n * 16 + (l & 15);
        float v = acc[m][n][q] + bias;
        v = v > 0.f ? v : 0.f;
        hid[(size_t)gm * DIM + gn] = f2bf(v);
      }
    }
  }
}

// ---- GEMM2 (BN=256, 512 thr, hid read ONCE): out = hid @ W2 + b2 (f32) ----
__global__ __launch_bounds__(512, 2) void k_gemm2(
    const unsigned short* __restrict__ hid,   // [MPAD][256] bf16
    const unsigned short* __restrict__ w2t,   // [256][256] bf16 (W2^T)
    const float* __restrict__ b2,
    float* __restrict__ out)
{
  __shared__ __align__(16) unsigned short Alds[128 * 64];   // 16 KB
  __shared__ __align__(16) unsigned short Blds[256 * 64];   // 32 KB

  const int tid = threadIdx.x;
  const int w = tid >> 6, l = tid & 63;
  const int m0 = blockIdx.x * 128;
  const int wm = w >> 2, wn = w & 3;          // 2M x 4N waves, 64x64 each
  const int srow = l >> 3, slot = l & 7;

  f32x4 acc[4][4] = {};

  for (int t = 0; t < 4; ++t) {
    __syncthreads();
#pragma unroll
    for (int i = 0; i < 2; ++i) {             // A: 128 rows
      int row = w * 16 + i * 8 + srow;
      int c = slot ^ (row & 7);
      gload16(hid + (size_t)(m0 + row) * DIM + (t << 6) + (c << 3),
              Alds + (w * 16 + i * 8) * 64);
    }
#pragma unroll
    for (int i = 0; i < 4; ++i) {             // B: 256 rows
      int row = w * 32 + i * 8 + srow;
      int c = slot ^ (row & 7);
      gload16(w2t + (size_t)row * DIM + (t << 6) + (c << 3),
              Blds + (w * 32 + i * 8) * 64);
    }
    __syncthreads();

#pragma unroll
    for (int kk = 0; kk < 2; ++kk) {
      bf16x8 af[4], bfr[4];
#pragma unroll
      for (int m = 0; m < 4; ++m) {
        int row = wm * 64 + m * 16 + (l & 15);
        int c = (kk * 4 + (l >> 4)) ^ (row & 7);
        af[m] = *(const bf16x8*)(Alds + row * 64 + c * 8);
      }
#pragma unroll
      for (int n = 0; n < 4; ++n) {
        int row = wn * 64 + n * 16 + (l & 15);
        int c = (kk * 4 + (l >> 4)) ^ (row & 7);
        bfr[n] = *(const bf16x8*)(Blds + row * 64 + c * 8);
      }
#pragma unroll
      for (int m = 0; m < 4; ++m)
#pragma unroll
        for (int n = 0; n < 4; ++n)
          acc[m][n] = __builtin_amdgcn_mfma_f32_16x16x32_bf16(af[m], bfr[n], acc[m][n], 0, 0, 0);
    }
  }

  // epilogue: bias -> f32; nf innermost => 256B contiguous per 16-lane group
  float bias0 = b2[wn * 64 + 0 * 16 + (l & 15)];
  float bias1 = b2[wn * 64 + 1 * 16 + (l & 15)];
  float bias2 = b2[wn * 64 + 2 * 16 + (l & 15)];
  float bias3 = b2[wn * 64 + 3 * 16 + (l & 15)];
#pragma unroll
  for (int m = 0; m < 4; ++m) {
#pragma unroll
    for (int q = 0; q < 4; ++q) {
      int gm = m0 + wm * 64 + m * 16 + (l >> 4) * 4 + q;
      if (gm < N_ABOVE) {
#pragma unroll
        for (int n = 0; n < 4; ++n) {
          float bias = n == 0 ? bias0 : n == 1 ? bias1 : n == 2 ? bias2 : bias3;
          int gn = wn * 64 + n * 16 + (l & 15);
          out[(size_t)gm * DIM + gn] = acc[m][n][q] + bias;
        }
      }
    }
  }
}

extern "C" void kernel_launch(void* const* d_in, const int* in_sizes, int n_in,
                              void* d_out, int out_size, void* d_ws, size_t ws_size,
                              hipStream_t stream) {
  const float* h    = (const float*)d_in[0];
  const int*   idx  = (const int*)d_in[2];
  const int*   jarr = (const int*)d_in[4];
  const float* W1   = (const float*)d_in[5];
  const float* b1   = (const float*)d_in[6];
  const float* W2   = (const float*)d_in[7];
  const float* b2   = (const float*)d_in[8];
  float* out = (float*)d_out;

  char* ws = (char*)d_ws;
  size_t off = 0;
  auto alloc = [&](size_t bytes) -> void* {
    void* p = ws + off;
    off += bytes;
    off = (off + 511) & ~(size_t)511;
    return p;
  };
  int*            inv = (int*)alloc((size_t)N_ABOVE * 4);
  unsigned short* hbf = (unsigned short*)alloc((size_t)(N_DOWN + 1) * DIM * 2);
  unsigned short* w1t = (unsigned short*)alloc((size_t)DIM * K1 * 2);
  unsigned short* w2t = (unsigned short*)alloc((size_t)DIM * DIM * 2);
  unsigned short* hid = (unsigned short*)alloc((size_t)MPAD * DIM * 2);
  if (ws_size < off) return;

  k_prep_inv<<<dim3(391), dim3(256), 0, stream>>>(inv, hbf);
  k_prep_all<<<dim3(12792), dim3(256), 0, stream>>>(h, idx, W1, W2, inv, hbf, w1t, w2t);
  k_gemm1<<<dim3(MPAD / 128, 2), dim3(256), 0, stream>>>(hbf, w1t, b1, inv, jarr, hid);
  k_gemm2<<<dim3(MPAD / 128), dim3(512), 0, stream>>>(hid, w2t, b2, out);
}